// Round 9
// baseline (2344.402 us; speedup 1.0000x reference)
//
#include <hip/hip_runtime.h>
#include <math.h>

#define N_NODES 100000
#define N_EDGES 1600000
#define HF 128
#define N_CLS 8
#define N_LAYERS 6
#define TILE_M 32
#define SCAN_B 1024
#define SCAN_NB ((N_NODES + SCAN_B - 1) / SCAN_B)   // 98
#define HBINS 8192
#define HCHUNK ((N_NODES + HBINS - 1) / HBINS)      // 13
#define HSLICE 8

typedef __attribute__((ext_vector_type(8))) short bf16x8;
typedef __attribute__((ext_vector_type(4))) float f32x4;

// RNE fp32 -> bf16 (bit exact), and back
__device__ __forceinline__ unsigned short bf_rne(float x) {
    unsigned u = __float_as_uint(x);
    u += 0x7FFFu + ((u >> 16) & 1u);
    return (unsigned short)(u >> 16);
}
__device__ __forceinline__ float bf_to_f(unsigned short h) {
    return __uint_as_float(((unsigned)h) << 16);
}

// swizzled LDS byte offset for bf16 tile [rows][128 k], 16B-unit XOR (T2)
#define LDSOFF(row, k) (((row) << 8) + (((((k) >> 3) << 4) ^ (((row) & 7) << 4))) + (((k) & 7) << 1))

// ---------------- in-degree histogram + per-edge rank (atomic return value) ----------------
__global__ void deg_rank_kernel(const int* __restrict__ dst,
                                int* __restrict__ ind, int* __restrict__ rank) {
    int e = blockIdx.x * blockDim.x + threadIdx.x;
    if (e < N_EDGES) {
        rank[e] = atomicAdd(&ind[dst[e]], 1);
    }
}

// ---------------- out-degree histogram via chunked LDS bins ----------------
__global__ __launch_bounds__(1024) void outdeg_hist_kernel(const int* __restrict__ src,
                                                           int* __restrict__ outd) {
    __shared__ int hist[HBINS];
    int chunk = blockIdx.x;
    int slice = blockIdx.y;
    int lo = chunk * HBINS;
    int hi = lo + HBINS;
    for (int i = threadIdx.x; i < HBINS; i += 1024) hist[i] = 0;
    __syncthreads();
    const int4* s4 = (const int4*)src;
    const int n4 = N_EDGES / 4;
    int per = (n4 + HSLICE - 1) / HSLICE;
    int beg = slice * per;
    int end = beg + per; if (end > n4) end = n4;
    for (int i = beg + threadIdx.x; i < end; i += 1024) {
        int4 v = s4[i];
        if (v.x >= lo && v.x < hi) atomicAdd(&hist[v.x - lo], 1);
        if (v.y >= lo && v.y < hi) atomicAdd(&hist[v.y - lo], 1);
        if (v.z >= lo && v.z < hi) atomicAdd(&hist[v.z - lo], 1);
        if (v.w >= lo && v.w < hi) atomicAdd(&hist[v.w - lo], 1);
    }
    __syncthreads();
    for (int i = threadIdx.x; i < HBINS; i += 1024) {
        int c = hist[i];
        if (c != 0 && lo + i < N_NODES) atomicAdd(&outd[lo + i], c);
    }
}

// ---------------- norms ----------------
__global__ void norm_kernel(const int* __restrict__ outd, const int* __restrict__ ind,
                            float* __restrict__ ns, float* __restrict__ nd) {
    int n = blockIdx.x * blockDim.x + threadIdx.x;
    if (n < N_NODES) {
        int od = outd[n]; if (od < 1) od = 1;
        int id = ind[n];  if (id < 1) id = 1;
        ns[n] = rsqrtf((float)od);
        nd[n] = rsqrtf((float)id);
    }
}

// ---------------- hierarchical scan ----------------
__global__ __launch_bounds__(SCAN_B) void scan1_kernel(const int* __restrict__ deg,
                                                       int* __restrict__ incl,
                                                       int* __restrict__ bsum) {
    __shared__ int buf[SCAN_B];
    int t = threadIdx.x;
    int g = blockIdx.x * SCAN_B + t;
    int v = (g < N_NODES) ? deg[g] : 0;
    buf[t] = v;
    __syncthreads();
    #pragma unroll
    for (int off = 1; off < SCAN_B; off <<= 1) {
        int add = (t >= off) ? buf[t - off] : 0;
        __syncthreads();
        buf[t] += add;
        __syncthreads();
    }
    if (g < N_NODES) incl[g] = buf[t];
    if (t == SCAN_B - 1) bsum[blockIdx.x] = buf[t];
}

__global__ __launch_bounds__(128) void scan2_kernel(int* __restrict__ bsum) {
    __shared__ int buf[128];
    int t = threadIdx.x;
    buf[t] = (t < SCAN_NB) ? bsum[t] : 0;
    __syncthreads();
    #pragma unroll
    for (int off = 1; off < 128; off <<= 1) {
        int add = (t >= off) ? buf[t - off] : 0;
        __syncthreads();
        buf[t] += add;
        __syncthreads();
    }
    if (t < SCAN_NB) bsum[t] = buf[t];
}

__global__ __launch_bounds__(SCAN_B) void scan3_kernel(const int* __restrict__ deg,
                                                       const int* __restrict__ incl,
                                                       const int* __restrict__ bsum,
                                                       int* __restrict__ row_ptr) {
    int t = threadIdx.x;
    int g = blockIdx.x * SCAN_B + t;
    if (g < N_NODES) {
        int off = (blockIdx.x > 0) ? bsum[blockIdx.x - 1] : 0;
        row_ptr[g] = off + incl[g] - deg[g];
    }
    if (g == 0) row_ptr[N_NODES] = bsum[SCAN_NB - 1];
}

// ------- scatter edges into CSR (atomic-free); pack (src,w*ns*nd) as float2 -------
__global__ void scatter2_kernel(const int* __restrict__ src, const int* __restrict__ dst,
                                const float* __restrict__ ew, const float* __restrict__ ns,
                                const float* __restrict__ nd, const int* __restrict__ row_ptr,
                                const int* __restrict__ rank, float2* __restrict__ esw) {
    int e = blockIdx.x * blockDim.x + threadIdx.x;
    if (e < N_EDGES) {
        int s = src[e];
        int d = dst[e];
        int pos = row_ptr[d] + rank[e];
        esw[pos] = make_float2(__int_as_float(s), ew[e] * ns[s] * nd[d]);
    }
}

// ------- W prep: split each layer's W[k][f] into 3 bf16 transposed mats Wt[f][k] -------
__global__ __launch_bounds__(256) void wprep_kernel(const float* __restrict__ conv_W,
                                                    unsigned short* __restrict__ wt) {
    int l = blockIdx.y;
    int idx = blockIdx.x * 256 + threadIdx.x;     // 0..16383
    int k = idx >> 7, f = idx & 127;
    float x = conv_W[(size_t)l * 16384 + idx];
    unsigned short h0 = bf_rne(x);
    float r1 = x - bf_to_f(h0);
    unsigned short h1 = bf_rne(r1);
    float r2 = r1 - bf_to_f(h1);
    unsigned short h2 = bf_rne(r2);
    size_t base = (size_t)l * 3 * 16384 + (size_t)f * 128 + k;
    wt[base]         = h0;
    wt[base + 16384] = h1;
    wt[base + 32768] = h2;
}

// ------- FUSED layer: h' = leaky( (S·h)·W + b )  -------
// phase 1: wave-per-node paired-float4 CSR gather -> g-tile, split to 3xbf16 in LDS
// phase 2: MFMA 16x16x32, 6-pass 3-term split (fp32-grade), bias+leaky epilogue
__global__ __launch_bounds__(256) void fused_layer_kernel(
        const float* __restrict__ hl, const int* __restrict__ row_ptr,
        const float2* __restrict__ esw, const unsigned short* __restrict__ Wt,
        const float* __restrict__ bias, float* __restrict__ out) {
    __shared__ unsigned short Xb[3][TILE_M * HF];   // 3 x 8 KB, XOR-swizzled
    int tid = threadIdx.x;
    int nodeBase = blockIdx.x * TILE_M;             // 100000 % 32 == 0: no tail
    int wv = tid >> 6;
    int lane = tid & 63;
    int half = lane >> 5;
    int fl = lane & 31;

    // ---- phase 1: gather 8 nodes per wave ----
    for (int idx = 0; idx < 8; idx++) {
        int lr = wv * 8 + idx;
        int node = nodeBase + lr;
        int beg = row_ptr[node];
        int end = row_ptr[node + 1];
        float ax = 0.f, ay = 0.f, az = 0.f, aw = 0.f;
        int i = beg;
        for (; i + 2 <= end; i += 2) {
            float2 p = esw[i + half];
            int s = __float_as_int(p.x);
            float4 v = ((const float4*)(hl + (size_t)s * HF))[fl];
            ax += v.x * p.y; ay += v.y * p.y;
            az += v.z * p.y; aw += v.w * p.y;
        }
        if (i < end && half == 0) {
            float2 p = esw[i];
            int s = __float_as_int(p.x);
            float4 v = ((const float4*)(hl + (size_t)s * HF))[fl];
            ax += v.x * p.y; ay += v.y * p.y;
            az += v.z * p.y; aw += v.w * p.y;
        }
        ax += __shfl_xor(ax, 32);
        ay += __shfl_xor(ay, 32);
        az += __shfl_xor(az, 32);
        aw += __shfl_xor(aw, 32);
        // both halves now hold the full sum; split to 3 bf16 terms
        float g[4] = {ax, ay, az, aw};
        unsigned short h0[4], h1[4], h2[4];
        #pragma unroll
        for (int j = 0; j < 4; j++) {
            h0[j] = bf_rne(g[j]);
            float r1 = g[j] - bf_to_f(h0[j]);
            h1[j] = bf_rne(r1);
            float r2 = r1 - bf_to_f(h1[j]);
            h2[j] = bf_rne(r2);
        }
        int boff = LDSOFF(lr, fl * 4) >> 1;
        if (half == 0) {
            *(uint2*)&Xb[0][boff] = *(uint2*)h0;
            *(uint2*)&Xb[1][boff] = *(uint2*)h1;
        } else {
            *(uint2*)&Xb[2][boff] = *(uint2*)h2;
        }
    }
    __syncthreads();

    // ---- phase 2: MFMA (proven R8 layout), M=32 ----
    int lrow = lane & 15;
    int lk8 = lane >> 4;

    f32x4 acc[2][2];
    #pragma unroll
    for (int m = 0; m < 2; m++)
        #pragma unroll
        for (int n = 0; n < 2; n++)
            acc[m][n] = (f32x4){0.f, 0.f, 0.f, 0.f};

    const int pa[6] = {0, 0, 1, 0, 1, 2};
    const int pb[6] = {0, 1, 0, 2, 1, 0};

    #pragma unroll
    for (int p = 0; p < 6; p++) {
        const unsigned short* xb = Xb[pa[p]];
        const unsigned short* wb = Wt + (size_t)pb[p] * 16384;
        #pragma unroll
        for (int ks = 0; ks < 4; ks++) {
            int k0 = ks * 32 + lk8 * 8;
            bf16x8 afr[2];
            #pragma unroll
            for (int m = 0; m < 2; m++) {
                int row = m * 16 + lrow;
                afr[m] = *(const bf16x8*)&xb[LDSOFF(row, k0) >> 1];
            }
            bf16x8 bfr[2];
            #pragma unroll
            for (int n = 0; n < 2; n++) {
                int col = wv * 32 + n * 16 + lrow;
                bfr[n] = *(const bf16x8*)&wb[col * 128 + k0];
            }
            #pragma unroll
            for (int m = 0; m < 2; m++)
                #pragma unroll
                for (int n = 0; n < 2; n++)
                    acc[m][n] = __builtin_amdgcn_mfma_f32_16x16x32_bf16(
                        afr[m], bfr[n], acc[m][n], 0, 0, 0);
        }
    }

    // epilogue: D col = lane&15 -> feat, row = 4*(lane>>4)+rr; bias + leaky
    #pragma unroll
    for (int n = 0; n < 2; n++) {
        int feat = wv * 32 + n * 16 + lrow;
        float bb = bias[feat];
        #pragma unroll
        for (int m = 0; m < 2; m++) {
            int rowBase = nodeBase + m * 16 + lk8 * 4;
            #pragma unroll
            for (int rr = 0; rr < 4; rr++) {
                float o = acc[m][n][rr] + bb;
                o = (o > 0.f) ? o : 0.01f * o;
                out[(size_t)(rowBase + rr) * HF + feat] = o;
            }
        }
    }
}

// ---------------- final projection: wave per node, 8 classes ----------------
__global__ __launch_bounds__(256) void proj_kernel(const float* __restrict__ h,
                                                   const float* __restrict__ W,
                                                   const float* __restrict__ b,
                                                   float* __restrict__ out) {
    int node = blockIdx.x * (blockDim.x >> 6) + (threadIdx.x >> 6);
    if (node >= N_NODES) return;
    int lane = threadIdx.x & 63;

    float2 v = *(const float2*)(h + (size_t)node * HF + lane * 2);
    float acc[N_CLS];
    #pragma unroll
    for (int c = 0; c < N_CLS; c++) {
        acc[c] = v.x * W[(lane * 2) * N_CLS + c] + v.y * W[(lane * 2 + 1) * N_CLS + c];
    }
    #pragma unroll
    for (int off = 32; off > 0; off >>= 1) {
        #pragma unroll
        for (int c = 0; c < N_CLS; c++) acc[c] += __shfl_down(acc[c], off);
    }
    if (lane == 0) {
        #pragma unroll
        for (int c = 0; c < N_CLS; c++) out[(size_t)node * N_CLS + c] = acc[c] + b[c];
    }
}

// ---------------- launch ----------------
extern "C" void kernel_launch(void* const* d_in, const int* in_sizes, int n_in,
                              void* d_out, int out_size, void* d_ws, size_t ws_size,
                              hipStream_t stream) {
    const float* in_feat = (const float*)d_in[0];
    const int*   src     = (const int*)d_in[1];
    const int*   dst     = (const int*)d_in[2];
    const float* ew      = (const float*)d_in[3];
    const float* conv_W  = (const float*)d_in[4];
    const float* conv_b  = (const float*)d_in[5];
    const float* lin_W   = (const float*)d_in[6];
    const float* lin_b   = (const float*)d_in[7];
    float* out = (float*)d_out;

    char* p = (char*)d_ws;
    float* hA = (float*)p;        p += (size_t)N_NODES * HF * sizeof(float);
    float* hB = (float*)p;        p += (size_t)N_NODES * HF * sizeof(float);
    float2* esw = (float2*)p;     p += (size_t)N_EDGES * sizeof(float2);
    int*   row_ptr = (int*)p;     p += ((size_t)N_NODES + 8) * sizeof(int);
    int*   out_deg = (int*)p;     p += (size_t)N_NODES * sizeof(int);
    int*   in_deg = (int*)p;      p += (size_t)N_NODES * sizeof(int);
    float* norm_src = (float*)p;  p += (size_t)N_NODES * sizeof(float);
    float* norm_dst = (float*)p;  p += (size_t)N_NODES * sizeof(float);
    int*   incl = (int*)p;        p += (size_t)N_NODES * sizeof(int);
    int*   bsum = (int*)p;        p += 256 * sizeof(int);
    unsigned short* wt = (unsigned short*)p; p += (size_t)N_LAYERS * 3 * 16384 * sizeof(unsigned short);
    // rank aliases hB: rank is fully consumed by scatter2 before layer 0 writes hB
    int*   rank = (int*)hB;
    (void)p; (void)ws_size; (void)in_sizes; (void)n_in; (void)out_size;

    hipMemsetAsync(out_deg, 0, (size_t)N_NODES * sizeof(int), stream);
    hipMemsetAsync(in_deg, 0, (size_t)N_NODES * sizeof(int), stream);

    int egrid = (N_EDGES + 255) / 256;
    int ngrid = (N_NODES + 255) / 256;

    deg_rank_kernel<<<egrid, 256, 0, stream>>>(dst, in_deg, rank);
    outdeg_hist_kernel<<<dim3(HCHUNK, HSLICE), 1024, 0, stream>>>(src, out_deg);
    norm_kernel<<<ngrid, 256, 0, stream>>>(out_deg, in_deg, norm_src, norm_dst);
    scan1_kernel<<<SCAN_NB, SCAN_B, 0, stream>>>(in_deg, incl, bsum);
    scan2_kernel<<<1, 128, 0, stream>>>(bsum);
    scan3_kernel<<<SCAN_NB, SCAN_B, 0, stream>>>(in_deg, incl, bsum, row_ptr);
    scatter2_kernel<<<egrid, 256, 0, stream>>>(src, dst, ew, norm_src, norm_dst,
                                               row_ptr, rank, esw);
    wprep_kernel<<<dim3(64, N_LAYERS), 256, 0, stream>>>(conv_W, wt);

    int fgrid = N_NODES / TILE_M;   // 3125, exact
    int agrid = (N_NODES + 3) / 4;

    const float* cur = in_feat;
    for (int l = 0; l < N_LAYERS; l++) {
        float* nxt = (l & 1) ? hA : hB;
        fused_layer_kernel<<<fgrid, 256, 0, stream>>>(cur, row_ptr, esw,
                                                      wt + (size_t)l * 3 * 16384,
                                                      conv_b + (size_t)l * HF, nxt);
        cur = nxt;
    }
    proj_kernel<<<agrid, 256, 0, stream>>>(hA, lin_W, lin_b, out);
}

// Round 11
// 1335.830 us; speedup vs baseline: 1.7550x; 1.7550x over previous
//
#include <hip/hip_runtime.h>
#include <math.h>

#define N_NODES 100000
#define N_EDGES 1600000
#define HF 128
#define N_CLS 8
#define N_LAYERS 6
#define TILE_N 64
#define NS 16                      // src stripes per node row
#define SDIV 6250                  // src ids per stripe (16*6250 = 100000)
#define NBINS (N_NODES * NS)       // 1,600,000 (dst, stripe) bins
#define SCAN_B 1024
#define SCAN_NB1 ((NBINS + SCAN_B - 1) / SCAN_B)    // 1563
#define HBINS 8192
#define HCHUNK ((N_NODES + HBINS - 1) / HBINS)      // 13
#define HSLICE 8

// ------- rank within (dst, src-stripe) bin + bin histogram (atomic return value) -------
__global__ void deg_rank_kernel(const int* __restrict__ src, const int* __restrict__ dst,
                                int* __restrict__ bins, int* __restrict__ rank) {
    int e = blockIdx.x * blockDim.x + threadIdx.x;
    if (e < N_EDGES) {
        int s = src[e];
        int d = dst[e];
        int bin = d * NS + s / SDIV;
        rank[e] = atomicAdd(&bins[bin], 1);
    }
}

// ---------------- out-degree histogram via chunked LDS bins ----------------
__global__ __launch_bounds__(1024) void outdeg_hist_kernel(const int* __restrict__ src,
                                                           int* __restrict__ outd) {
    __shared__ int hist[HBINS];
    int chunk = blockIdx.x;
    int slice = blockIdx.y;
    int lo = chunk * HBINS;
    int hi = lo + HBINS;
    for (int i = threadIdx.x; i < HBINS; i += 1024) hist[i] = 0;
    __syncthreads();
    const int4* s4 = (const int4*)src;
    const int n4 = N_EDGES / 4;
    int per = (n4 + HSLICE - 1) / HSLICE;
    int beg = slice * per;
    int end = beg + per; if (end > n4) end = n4;
    for (int i = beg + threadIdx.x; i < end; i += 1024) {
        int4 v = s4[i];
        if (v.x >= lo && v.x < hi) atomicAdd(&hist[v.x - lo], 1);
        if (v.y >= lo && v.y < hi) atomicAdd(&hist[v.y - lo], 1);
        if (v.z >= lo && v.z < hi) atomicAdd(&hist[v.z - lo], 1);
        if (v.w >= lo && v.w < hi) atomicAdd(&hist[v.w - lo], 1);
    }
    __syncthreads();
    for (int i = threadIdx.x; i < HBINS; i += 1024) {
        int c = hist[i];
        if (c != 0 && lo + i < N_NODES) atomicAdd(&outd[lo + i], c);
    }
}

// ---------------- norms: in-degree from sptr row extents ----------------
__global__ void norm_kernel(const int* __restrict__ outd, const int* __restrict__ sptr,
                            float* __restrict__ ns, float* __restrict__ nd) {
    int n = blockIdx.x * blockDim.x + threadIdx.x;
    if (n < N_NODES) {
        int od = outd[n]; if (od < 1) od = 1;
        int id = sptr[(n + 1) * NS] - sptr[n * NS];
        if (id < 1) id = 1;
        ns[n] = rsqrtf((float)od);
        nd[n] = rsqrtf((float)id);
    }
}

// ---------------- hierarchical scan over NBINS ----------------
__global__ __launch_bounds__(SCAN_B) void scan1_kernel(const int* __restrict__ deg,
                                                       int* __restrict__ incl,
                                                       int* __restrict__ bsum) {
    __shared__ int buf[SCAN_B];
    int t = threadIdx.x;
    int g = blockIdx.x * SCAN_B + t;
    int v = (g < NBINS) ? deg[g] : 0;
    buf[t] = v;
    __syncthreads();
    #pragma unroll
    for (int off = 1; off < SCAN_B; off <<= 1) {
        int add = (t >= off) ? buf[t - off] : 0;
        __syncthreads();
        buf[t] += add;
        __syncthreads();
    }
    if (g < NBINS) incl[g] = buf[t];
    if (t == SCAN_B - 1) bsum[blockIdx.x] = buf[t];
}

// scan block sums (SCAN_NB1 = 1563 elements) in one block, chunked with carry
__global__ __launch_bounds__(1024) void scan2_kernel(int* __restrict__ bsum) {
    __shared__ int buf[1024];
    __shared__ int carry_s;
    int t = threadIdx.x;
    if (t == 0) carry_s = 0;
    __syncthreads();
    for (int base = 0; base < SCAN_NB1; base += 1024) {
        int v = (base + t < SCAN_NB1) ? bsum[base + t] : 0;
        buf[t] = v;
        __syncthreads();
        #pragma unroll
        for (int off = 1; off < 1024; off <<= 1) {
            int add = (t >= off) ? buf[t - off] : 0;
            __syncthreads();
            buf[t] += add;
            __syncthreads();
        }
        int incl = buf[t];
        int carry = carry_s;
        if (base + t < SCAN_NB1) bsum[base + t] = carry + incl;
        __syncthreads();
        if (t == 1023) carry_s = carry + incl;
        __syncthreads();
    }
}

__global__ __launch_bounds__(SCAN_B) void scan3_kernel(const int* __restrict__ deg,
                                                       const int* __restrict__ incl,
                                                       const int* __restrict__ bsum,
                                                       int* __restrict__ sptr) {
    int t = threadIdx.x;
    int g = blockIdx.x * SCAN_B + t;
    if (g < NBINS) {
        int off = (blockIdx.x > 0) ? bsum[blockIdx.x - 1] : 0;
        sptr[g] = off + incl[g] - deg[g];
    }
    if (g == 0) sptr[NBINS] = bsum[SCAN_NB1 - 1];
}

// ------- scatter edges into stripe-sorted CSR; pack (src, w*ns*nd) as float2 -------
__global__ void scatter2_kernel(const int* __restrict__ src, const int* __restrict__ dst,
                                const float* __restrict__ ew, const float* __restrict__ ns,
                                const float* __restrict__ nd, const int* __restrict__ sptr,
                                const int* __restrict__ rank, float2* __restrict__ esw) {
    int e = blockIdx.x * blockDim.x + threadIdx.x;
    if (e < N_EDGES) {
        int s = src[e];
        int d = dst[e];
        int pos = sptr[d * NS + s / SDIV] + rank[e];
        esw[pos] = make_float2(__int_as_float(s), ew[e] * ns[s] * nd[d]);
    }
}

// ---------------- fp32 GEMM (R4 shape): Y[n][f] = sum_k X[n][k] W[k][f] ----------------
__global__ __launch_bounds__(256) void gemm_kernel(const float* __restrict__ X,
                                                   const float* __restrict__ W,
                                                   float* __restrict__ Y) {
    __shared__ float Xs[TILE_N][HF];   // 32 KB
    int tid = threadIdx.x;
    int nodeBase = blockIdx.x * TILE_N;

    for (int i = tid; i < TILE_N * (HF / 4); i += 256) {
        int r = i >> 5;
        int c = i & 31;
        int n = nodeBase + r;
        float4 v = make_float4(0.f, 0.f, 0.f, 0.f);
        if (n < N_NODES) v = ((const float4*)(X + (size_t)n * HF))[c];
        ((float4*)(&Xs[r][0]))[c] = v;
    }
    __syncthreads();

    int tx = tid & 31;
    int ty = tid >> 5;

    float acc[8][4];
    #pragma unroll
    for (int i = 0; i < 8; i++)
        #pragma unroll
        for (int j = 0; j < 4; j++) acc[i][j] = 0.f;

    const float4* W4 = (const float4*)W;

    for (int k4 = 0; k4 < HF / 4; k4++) {
        float4 wv0 = W4[(k4 * 4 + 0) * 32 + tx];
        float4 wv1 = W4[(k4 * 4 + 1) * 32 + tx];
        float4 wv2 = W4[(k4 * 4 + 2) * 32 + tx];
        float4 wv3 = W4[(k4 * 4 + 3) * 32 + tx];
        #pragma unroll
        for (int i = 0; i < 8; i++) {
            float4 xv = ((const float4*)(&Xs[ty + 8 * i][0]))[k4];
            acc[i][0] += xv.x * wv0.x; acc[i][1] += xv.x * wv0.y;
            acc[i][2] += xv.x * wv0.z; acc[i][3] += xv.x * wv0.w;
            acc[i][0] += xv.y * wv1.x; acc[i][1] += xv.y * wv1.y;
            acc[i][2] += xv.y * wv1.z; acc[i][3] += xv.y * wv1.w;
            acc[i][0] += xv.z * wv2.x; acc[i][1] += xv.z * wv2.y;
            acc[i][2] += xv.z * wv2.z; acc[i][3] += xv.z * wv2.w;
            acc[i][0] += xv.w * wv3.x; acc[i][1] += xv.w * wv3.y;
            acc[i][2] += xv.w * wv3.z; acc[i][3] += xv.w * wv3.w;
        }
    }

    #pragma unroll
    for (int i = 0; i < 8; i++) {
        int n = nodeBase + ty + 8 * i;
        if (n < N_NODES) {
            float4 o = make_float4(acc[i][0], acc[i][1], acc[i][2], acc[i][3]);
            ((float4*)(Y + (size_t)n * HF))[tx] = o;
        }
    }
}

// ------- aggregation: wave per node, paired float4 gathers over src-sorted row -------
__global__ __launch_bounds__(256) void agg_kernel(const float* __restrict__ hl,
                                                  const int* __restrict__ sptr,
                                                  const float2* __restrict__ esw,
                                                  const float* __restrict__ bias,
                                                  float* __restrict__ out) {
    int node = blockIdx.x * 4 + (threadIdx.x >> 6);
    if (node >= N_NODES) return;
    int lane = threadIdx.x & 63;
    int half = lane >> 5;
    int fl = lane & 31;

    int beg = sptr[node * NS];
    int end = sptr[node * NS + NS];
    float ax = 0.f, ay = 0.f, az = 0.f, aw = 0.f;

    int i = beg;
    for (; i + 2 <= end; i += 2) {
        float2 p = esw[i + half];
        int s = __float_as_int(p.x);
        float4 v = ((const float4*)(hl + (size_t)s * HF))[fl];
        ax += v.x * p.y; ay += v.y * p.y;
        az += v.z * p.y; aw += v.w * p.y;
    }
    if (i < end && half == 0) {
        float2 p = esw[i];
        int s = __float_as_int(p.x);
        float4 v = ((const float4*)(hl + (size_t)s * HF))[fl];
        ax += v.x * p.y; ay += v.y * p.y;
        az += v.z * p.y; aw += v.w * p.y;
    }

    ax += __shfl_xor(ax, 32);
    ay += __shfl_xor(ay, 32);
    az += __shfl_xor(az, 32);
    aw += __shfl_xor(aw, 32);

    if (half == 0) {
        float4 bb = ((const float4*)bias)[fl];
        float ox = ax + bb.x;
        float oy = ay + bb.y;
        float oz = az + bb.z;
        float ow = aw + bb.w;
        ox = (ox > 0.f) ? ox : 0.01f * ox;
        oy = (oy > 0.f) ? oy : 0.01f * oy;
        oz = (oz > 0.f) ? oz : 0.01f * oz;
        ow = (ow > 0.f) ? ow : 0.01f * ow;
        ((float4*)(out + (size_t)node * HF))[fl] = make_float4(ox, oy, oz, ow);
    }
}

// ---------------- final projection: wave per node, 8 classes ----------------
__global__ __launch_bounds__(256) void proj_kernel(const float* __restrict__ h,
                                                   const float* __restrict__ W,
                                                   const float* __restrict__ b,
                                                   float* __restrict__ out) {
    int node = blockIdx.x * (blockDim.x >> 6) + (threadIdx.x >> 6);
    if (node >= N_NODES) return;
    int lane = threadIdx.x & 63;

    float2 v = *(const float2*)(h + (size_t)node * HF + lane * 2);
    float acc[N_CLS];
    #pragma unroll
    for (int c = 0; c < N_CLS; c++) {
        acc[c] = v.x * W[(lane * 2) * N_CLS + c] + v.y * W[(lane * 2 + 1) * N_CLS + c];
    }
    #pragma unroll
    for (int off = 32; off > 0; off >>= 1) {
        #pragma unroll
        for (int c = 0; c < N_CLS; c++) acc[c] += __shfl_down(acc[c], off);
    }
    if (lane == 0) {
        #pragma unroll
        for (int c = 0; c < N_CLS; c++) out[(size_t)node * N_CLS + c] = acc[c] + b[c];
    }
}

// ---------------- launch ----------------
extern "C" void kernel_launch(void* const* d_in, const int* in_sizes, int n_in,
                              void* d_out, int out_size, void* d_ws, size_t ws_size,
                              hipStream_t stream) {
    const float* in_feat = (const float*)d_in[0];
    const int*   src     = (const int*)d_in[1];
    const int*   dst     = (const int*)d_in[2];
    const float* ew      = (const float*)d_in[3];
    const float* conv_W  = (const float*)d_in[4];
    const float* conv_b  = (const float*)d_in[5];
    const float* lin_W   = (const float*)d_in[6];
    const float* lin_b   = (const float*)d_in[7];
    float* out = (float*)d_out;

    char* p = (char*)d_ws;
    float* hA = (float*)p;        p += (size_t)N_NODES * HF * sizeof(float);
    float* hB = (float*)p;        p += (size_t)N_NODES * HF * sizeof(float);
    float2* esw = (float2*)p;     p += (size_t)N_EDGES * sizeof(float2);
    int*   sptr = (int*)p;        p += ((size_t)NBINS + 8) * sizeof(int);
    int*   bsum = (int*)p;        p += ((size_t)SCAN_NB1 + 8) * sizeof(int);
    int*   out_deg = (int*)p;     p += (size_t)N_NODES * sizeof(int);
    float* norm_src = (float*)p;  p += (size_t)N_NODES * sizeof(float);
    float* norm_dst = (float*)p;  p += (size_t)N_NODES * sizeof(float);
    (void)p; (void)ws_size; (void)in_sizes; (void)n_in; (void)out_size;

    // big scratch aliased into hA/hB (all dead before first layer writes them):
    int* rank = (int*)hB;                      // 6.4 MB, used through scatter2
    int* bins = (int*)hA;                      // 6.4 MB bin degrees
    int* incl = (int*)hA + 2000000;            // 6.4 MB inclusive scan (8 MB offset)

    hipMemsetAsync(bins, 0, (size_t)NBINS * sizeof(int), stream);
    hipMemsetAsync(out_deg, 0, (size_t)N_NODES * sizeof(int), stream);

    int egrid = (N_EDGES + 255) / 256;
    int ngrid = (N_NODES + 255) / 256;

    deg_rank_kernel<<<egrid, 256, 0, stream>>>(src, dst, bins, rank);
    outdeg_hist_kernel<<<dim3(HCHUNK, HSLICE), 1024, 0, stream>>>(src, out_deg);
    scan1_kernel<<<SCAN_NB1, SCAN_B, 0, stream>>>(bins, incl, bsum);
    scan2_kernel<<<1, 1024, 0, stream>>>(bsum);
    scan3_kernel<<<SCAN_NB1, SCAN_B, 0, stream>>>(bins, incl, bsum, sptr);
    norm_kernel<<<ngrid, 256, 0, stream>>>(out_deg, sptr, norm_src, norm_dst);
    scatter2_kernel<<<egrid, 256, 0, stream>>>(src, dst, ew, norm_src, norm_dst,
                                               sptr, rank, esw);

    int ggrid = (N_NODES + TILE_N - 1) / TILE_N;
    int agrid = (N_NODES + 3) / 4;

    const float* cur = in_feat;
    for (int l = 0; l < N_LAYERS; l++) {
        gemm_kernel<<<ggrid, 256, 0, stream>>>(cur, conv_W + (size_t)l * HF * HF, hB);
        agg_kernel<<<agrid, 256, 0, stream>>>(hB, sptr, esw,
                                              conv_b + (size_t)l * HF, hA);
        cur = hA;
    }
    proj_kernel<<<agrid, 256, 0, stream>>>(hA, lin_W, lin_b, out);
}